// Round 7
// baseline (133.373 us; speedup 1.0000x reference)
//
#include <hip/hip_runtime.h>
#include <math.h>

typedef __attribute__((ext_vector_type(8))) short bf16x8;
typedef _Float16 f16x8 __attribute__((ext_vector_type(8)));
typedef __attribute__((ext_vector_type(4))) float f32x4;

#define PI_F 3.14159265358979323846f

__device__ __forceinline__ unsigned short f2bf(float f) {
  unsigned int u = __float_as_uint(f);
  u += 0x7FFFu + ((u >> 16) & 1u);   // RNE to bf16
  return (unsigned short)(u >> 16);
}

__device__ __forceinline__ float bf2f(unsigned short u) {
  return __uint_as_float(((unsigned int)u) << 16);
}

__device__ __forceinline__ void async_ld16(const unsigned short* g, unsigned short* l) {
  __builtin_amdgcn_global_load_lds(
      (const __attribute__((address_space(1))) void*)g,
      (__attribute__((address_space(3))) void*)l,
      16, 0, 0);
}

// fast erf, A&S 7.1.26, |err| <= 1.5e-7 absolute
__device__ __forceinline__ float fast_erf(float x) {
  float a = fabsf(x);
  float t = 1.0f / fmaf(0.3275911f, a, 1.0f);
  float p = t * fmaf(t, fmaf(t, fmaf(t, fmaf(t, 1.061405429f, -1.453152027f),
                                     1.421413741f), -0.284496736f), 0.254829592f);
  float e = __expf(-a * a);
  float r = 1.0f - p * e;
  return copysignf(r, x);
}

__device__ __forceinline__ float fast_tanh(float a) {
  float e = __expf(2.0f * a);
  return 1.0f - 2.0f / (e + 1.0f);
}

// RX on stored basis: XOR-pair (lane-mask ML, register-mask MR); RX matrix symmetric.
template<int ML, int MR>
__device__ __forceinline__ void apply_rx(float re[4], float im[4], float c, float s) {
  float pr[4], pi[4];
  #pragma unroll
  for (int r = 0; r < 4; r++) {
    float vr = re[r ^ MR], vi = im[r ^ MR];
    if (ML) { vr = __shfl_xor(vr, ML, 64); vi = __shfl_xor(vi, ML, 64); }
    pr[r] = vr; pi[r] = vi;
  }
  #pragma unroll
  for (int r = 0; r < 4; r++) {
    re[r] = fmaf(c, re[r],  s * pi[r]);
    im[r] = fmaf(c, im[r], -s * pr[r]);
  }
}

// ---------------- prep: adj/Wg cvt, U-builder (interleaved), G-builder, x transpose ----
// blocks [0,1024): adj cvt; [1024,1088): Wg cvt; [1088,1152): U-builder;
// [1152,1168): G-builder; [1168,5264): x transpose (16,1024,256)->(4096,1024) bf16.
// Transpose vectorized (G13): float4 reads + ushort4 stores.
__global__ __launch_bounds__(256)
void prep_kernel(const float* __restrict__ adj, unsigned short* __restrict__ adj_bf,
                 const float* __restrict__ Wg, unsigned short* __restrict__ Wg_bf,
                 const float* __restrict__ qw, unsigned short* __restrict__ Uri,
                 const float* __restrict__ Wpost, _Float16* __restrict__ Gt,
                 const float* __restrict__ x, unsigned short* __restrict__ xT) {
  __shared__ float smem[1056];
  int bid = blockIdx.x, t = threadIdx.x;
  if (bid < 1024) {
    int i = bid * 256 + t;
    float4 v = ((const float4*)adj)[i];
    ushort4 o; o.x = f2bf(v.x); o.y = f2bf(v.y); o.z = f2bf(v.z); o.w = f2bf(v.w);
    ((ushort4*)adj_bf)[i] = o;
  } else if (bid < 1088) {
    int i = (bid - 1024) * 256 + t;
    float4 v = ((const float4*)Wg)[i];
    ushort4 o; o.x = f2bf(v.x); o.y = f2bf(v.y); o.z = f2bf(v.z); o.w = f2bf(v.w);
    ((ushort4*)Wg_bf)[i] = o;
  } else if (bid < 1152) {
    // U-builder: simulate entangler on basis k. CNOT rings deferred (linear maps);
    // layer-2 RX masks = R^-1 e_w; logical index n = R^2 s (rows of R^2 below).
    // Output layout INTERLEAVED by 16-blocks: row (n>>4)*32 + (n&15)      = Ure[n][*]
    //                                         row (n>>4)*32 + 16 + (n&15) = Uim[n][*]
    if (t < 16) { smem[t] = cosf(0.5f * qw[t]); smem[16 + t] = sinf(0.5f * qw[t]); }
    __syncthreads();
    int wv = t >> 6, L = t & 63;
    int k = (bid - 1088) * 4 + wv;
    float re[4], im[4];
    #pragma unroll
    for (int r = 0; r < 4; r++) { re[r] = (r * 64 + L == k) ? 1.f : 0.f; im[r] = 0.f; }
    // layer 1 RX (F = I)
    apply_rx<1, 0>(re, im, smem[0], smem[16]);
    apply_rx<2, 0>(re, im, smem[1], smem[17]);
    apply_rx<4, 0>(re, im, smem[2], smem[18]);
    apply_rx<8, 0>(re, im, smem[3], smem[19]);
    apply_rx<16, 0>(re, im, smem[4], smem[20]);
    apply_rx<32, 0>(re, im, smem[5], smem[21]);
    apply_rx<0, 1>(re, im, smem[6], smem[22]);
    apply_rx<0, 2>(re, im, smem[7], smem[23]);
    // layer 2 RX (F = R): masks R^-1 e_w
    apply_rx<3, 0>(re, im, smem[8], smem[24]);
    apply_rx<6, 0>(re, im, smem[9], smem[25]);
    apply_rx<12, 0>(re, im, smem[10], smem[26]);
    apply_rx<24, 0>(re, im, smem[11], smem[27]);
    apply_rx<48, 0>(re, im, smem[12], smem[28]);
    apply_rx<32, 1>(re, im, smem[13], smem[29]);
    apply_rx<0, 3>(re, im, smem[14], smem[30]);
    apply_rx<3, 2>(re, im, smem[15], smem[31]);
    const int M[8] = {0xAB, 0xFD, 0xFA, 0xF5, 0xEA, 0xD5, 0xAA, 0x55};
    #pragma unroll
    for (int r = 0; r < 4; r++) {
      int n = 0;
      #pragma unroll
      for (int w = 0; w < 8; w++) {
        int bit = (__popc(L & (M[w] & 63)) ^ __popc((r << 6) & M[w])) & 1;
        n |= bit << w;
      }
      int row_re = ((n >> 4) << 5) + (n & 15);
      Uri[(size_t)row_re * 256 + k] = f2bf(re[r]);
      Uri[(size_t)(row_re + 16) * 256 + k] = f2bf(im[r]);
    }
  } else if (bid < 1168) {
    // G-builder: Gt[h][n] = sum_w (-1)^{bit_w(n)} Wpost[h][w]  (f16)
    int tid = (bid - 1152) * 256 + t;   // [0,4096)
    int h = tid >> 4;
    int n0 = (tid & 15) << 4;
    float wv8[8];
    #pragma unroll
    for (int w = 0; w < 8; w++) wv8[w] = Wpost[h * 8 + w];
    #pragma unroll
    for (int j = 0; j < 16; j++) {
      int n = n0 + j;
      float sum = 0.f;
      #pragma unroll
      for (int w = 0; w < 8; w++) sum += ((n >> w) & 1) ? -wv8[w] : wv8[w];
      Gt[h * 256 + n] = (_Float16)sum;
    }
  } else {
    // x transpose, vectorized: 32x32 tile; float4 read, ushort4 write.
    int tb = bid - 1168;
    int jt = tb & 31, ht = (tb >> 5) & 7, bb = tb >> 8;
    const float* xb = x + (size_t)bb * 1024 * 256;
    int row = t >> 3, cg = t & 7;        // row 0..31, col-group 0..7 (4 cols each)
    {
      float4 v = *(const float4*)&xb[(size_t)(jt * 32 + row) * 256 + ht * 32 + cg * 4];
      smem[row * 33 + cg * 4 + 0] = v.x;
      smem[row * 33 + cg * 4 + 1] = v.y;
      smem[row * 33 + cg * 4 + 2] = v.z;
      smem[row * 33 + cg * 4 + 3] = v.w;
    }
    __syncthreads();
    unsigned short* xTb = xT + (size_t)bb * 256 * 1024;
    int h = ht * 32 + row;
    ushort4 o;
    o.x = f2bf(smem[(cg * 4 + 0) * 33 + row]);
    o.y = f2bf(smem[(cg * 4 + 1) * 33 + row]);
    o.z = f2bf(smem[(cg * 4 + 2) * 33 + row]);
    o.w = f2bf(smem[(cg * 4 + 3) * 33 + row]);
    *(ushort4*)&xTb[(size_t)h * 1024 + jt * 32 + cg * 4] = o;
  }
}

// ---------------- gemm1: C = A * Bt^T, tile 128(M) x 128(N), BK=64, DOUBLE-BUFFERED ----
// 256 blocks, 256 thr (4 waves, each 64x64 out). LDS 64 KB -> 2 blocks/CU so two
// blocks' barrier phases interleave. Staged traffic 131 MB (vs 197 at 64x128) and
// 32 MFMA/wave/step (~160 cy) covers most of the L2 load window under the dbuf.
// XCD-chunked swizzle (256 % 8 == 0, bijective): each XCD's 32 blocks share 4
// B-panels + all 8 A-panels (3 MB) in its private L2.
// LDS chunks XOR-swizzled via pre-swizzled GLOBAL source (dest stays linear).
__global__ __launch_bounds__(256)
void gemm1_kernel(const unsigned short* __restrict__ A,
                  const unsigned short* __restrict__ Bt,
                  unsigned short* __restrict__ C,
                  int K, int tilesN, int ldC) {
  __shared__ unsigned short As[2 * 2 * 128 * 32];   // 32 KB [buf][kb][128][32]
  __shared__ unsigned short Bs[2 * 2 * 128 * 32];   // 32 KB
  int bid = blockIdx.x;
  int swz = (bid & 7) * 32 + (bid >> 3);   // XCD-chunked
  int in_ = swz >> 3;    // 0..31  N-tile (128 cols)
  int im  = swz & 7;     // 0..7   M-tile (128 rows)
  const unsigned short* Ab  = A  + (long long)im * 128 * K;
  const unsigned short* Btb = Bt + (long long)in_ * 128 * K;

  int t = threadIdx.x;
  int wv = t >> 6, lane = t & 63;
  int wm = wv >> 1, wn = wv & 1;
  int l15 = lane & 15, quad = lane >> 4;

  // staging: per (kb, matrix) 512 slots of 16B -> 2 per thread (t, 256+t)
  int r0 = t >> 2,         c0 = (t & 3) ^ ((r0 >> 1) & 3);
  int r1 = (256 + t) >> 2, c1 = (t & 3) ^ ((r1 >> 1) & 3);
  long long go0 = (long long)r0 * K + c0 * 8;
  long long go1 = (long long)r1 * K + c1 * 8;

  f32x4 acc[4][4] = {};

  // prologue: stage buf0 @ kk=0
  #pragma unroll
  for (int kb = 0; kb < 2; kb++) {
    async_ld16(Ab + go0 + kb * 32, &As[kb * 4096 + t * 8]);
    async_ld16(Ab + go1 + kb * 32, &As[kb * 4096 + (256 + t) * 8]);
    async_ld16(Btb + go0 + kb * 32, &Bs[kb * 4096 + t * 8]);
    async_ld16(Btb + go1 + kb * 32, &Bs[kb * 4096 + (256 + t) * 8]);
  }
  __syncthreads();

  int nk = K >> 6;
  for (int ki = 0; ki < nk; ki++) {
    int buf = ki & 1;
    if (ki + 1 < nk) {           // issue next tile's loads BEFORE compute
      int nb = buf ^ 1;
      long long kk = (long long)(ki + 1) << 6;
      #pragma unroll
      for (int kb = 0; kb < 2; kb++) {
        async_ld16(Ab + go0 + kk + kb * 32, &As[nb * 8192 + kb * 4096 + t * 8]);
        async_ld16(Ab + go1 + kk + kb * 32, &As[nb * 8192 + kb * 4096 + (256 + t) * 8]);
        async_ld16(Btb + go0 + kk + kb * 32, &Bs[nb * 8192 + kb * 4096 + t * 8]);
        async_ld16(Btb + go1 + kk + kb * 32, &Bs[nb * 8192 + kb * 4096 + (256 + t) * 8]);
      }
    }
    #pragma unroll
    for (int kb = 0; kb < 2; kb++) {
      bf16x8 af[4], bfr[4];
      #pragma unroll
      for (int mt = 0; mt < 4; mt++) {
        int row = wm * 64 + mt * 16 + l15;
        af[mt] = *(const bf16x8*)&As[buf * 8192 + kb * 4096 + row * 32 +
                                     ((quad ^ ((row >> 1) & 3)) * 8)];
      }
      #pragma unroll
      for (int nt = 0; nt < 4; nt++) {
        int row = wn * 64 + nt * 16 + l15;
        bfr[nt] = *(const bf16x8*)&Bs[buf * 8192 + kb * 4096 + row * 32 +
                                      ((quad ^ ((row >> 1) & 3)) * 8)];
      }
      #pragma unroll
      for (int mt = 0; mt < 4; mt++)
        #pragma unroll
        for (int nt = 0; nt < 4; nt++)
          acc[mt][nt] = __builtin_amdgcn_mfma_f32_16x16x32_bf16(af[mt], bfr[nt], acc[mt][nt], 0, 0, 0);
    }
    __syncthreads();   // drains this step's prefetch (overlapped with the MFMAs above)
  }

  int n0 = in_ * 128;
  #pragma unroll
  for (int mt = 0; mt < 4; mt++) {
    #pragma unroll
    for (int nt = 0; nt < 4; nt++) {
      int colg = n0 + wn * 64 + nt * 16 + l15;
      #pragma unroll
      for (int r = 0; r < 4; r++) {
        int rowg = im * 128 + wm * 64 + mt * 16 + quad * 4 + r;
        C[(size_t)rowg * ldC + colg] = f2bf(acc[mt][nt][r]);
      }
    }
  }
}

// ---------------- qfused: g-GEMM + GELU + MFMA-angles + P0 + S-GEMM + |S|^2 + out-GEMM ----
// 256 blocks x 1024 thr (16 waves); block owns 64 samples. 1 block/CU, 4 waves/SIMD.
// Barrier-shadow loads: all 8 Wg frags preloaded above the As DMA barrier (fly under
// the HBM wait); first Uri frags hoisted above the P0s barrier; Gt frags above the Ts
// barrier. Same loads, same consumption order -> bit-identical numerics.
// LDS 100 KB: As 32K | gs|Ts 32K | P0s(prt) 32K | csw 4K
__global__ __launch_bounds__(1024, 4)
void qfused_kernel(const unsigned short* __restrict__ xagg,
                   const unsigned short* __restrict__ Wg,
                   const float* __restrict__ bg,
                   const float* __restrict__ Wpre, const float* __restrict__ bpre,
                   const unsigned short* __restrict__ Uri,
                   const _Float16* __restrict__ Gt,
                   const float* __restrict__ bpost,
                   float* __restrict__ out) {
  __shared__ __align__(16) char smemraw[102400];
  unsigned short* As  = (unsigned short*)smemraw;            // 32 KB swz panels [8][64][32] bf16
  unsigned short* gs  = (unsigned short*)(smemraw + 32768);  // 32 KB swz panels [8][64][32] bf16
  _Float16*       Ts  = (_Float16*)(smemraw + 32768);        //   (reused: f16 T panels, same swz)
  unsigned short* P0s = (unsigned short*)(smemraw + 65536);  // 32 KB swz panels
  float*          prt = (float*)(smemraw + 65536);           //   (early reuse: [8][64][8] f32 partials)
  float*          csw = (float*)(smemraw + 98304);           // 4 KB [64][16]: cw[8] | sw[8] per row

  int t = threadIdx.x;
  int wv = t >> 6, lane = t & 63;
  int l15 = lane & 15, quad = lane >> 4;

  const unsigned short* Ab = xagg + (size_t)blockIdx.x * 64 * 256;

  // ---- stage xagg A-tile (64x256) into LDS ONCE (issue), then preload ALL Wg
  //      fragments for this wave's columns so they fly under the DMA wait ----
  #pragma unroll
  for (int q = 0; q < 2; q++) {
    int sidx = q * 1024 + t;           // 0..2047 slots of 16B
    int kb = sidx >> 8;                // k-panel 0..7
    int r  = (sidx >> 2) & 63;         // row 0..63
    int c  = (sidx & 3) ^ ((r >> 1) & 3);
    async_ld16(Ab + (size_t)r * 256 + kb * 32 + c * 8, &As[sidx * 8]);
  }
  const unsigned short* Wp = Wg + (size_t)(wv * 16 + l15) * 256 + quad * 8;
  bf16x8 wf[8];
  #pragma unroll
  for (int k8 = 0; k8 < 8; k8++) wf[k8] = *(const bf16x8*)(Wp + k8 * 32);
  __syncthreads();   // As ready (Wg frags arrived during the same drain)

  // ---- stage A: g = GELU(xagg @ Wg^T + bg); wave wv owns cols wv*16..+15 ----
  f32x4 acc[4] = {};
  #pragma unroll
  for (int k8 = 0; k8 < 8; k8++) {
    #pragma unroll
    for (int mt = 0; mt < 4; mt++) {
      int row = mt * 16 + l15;
      bf16x8 af = *(const bf16x8*)&As[k8 * 2048 + row * 32 + ((quad ^ ((row >> 1) & 3)) * 8)];
      acc[mt] = __builtin_amdgcn_mfma_f32_16x16x32_bf16(af, wf[k8], acc[mt], 0, 0, 0);
    }
  }
  {
    int col = wv * 16 + l15;
    float bgl = bg[col];
    int kbc = col >> 5, chunk = (col >> 3) & 3, e = col & 7;
    #pragma unroll
    for (int mt = 0; mt < 4; mt++) {
      #pragma unroll
      for (int r = 0; r < 4; r++) {
        int row = mt * 16 + quad * 4 + r;
        float v = acc[mt][r] + bgl;
        v = 0.5f * v * (1.0f + fast_erf(v * 0.7071067811865475f));
        *(unsigned short*)((char*)gs + kbc * 4096 + row * 64 +
                           ((chunk ^ ((row >> 1) & 3)) << 4) + e * 2) = f2bf(v);
      }
    }
  }
  __syncthreads();   // gs complete

  // ---- angle GEMM: ang = g @ Wpre^T; wave pair (k8 = wv>>1) x M-half (mh = wv&1) ----
  {
    int k8 = wv >> 1, mh = wv & 1;
    const float* wrow = Wpre + (size_t)(l15 & 7) * 256 + k8 * 32 + quad * 8;
    float4 wa = *(const float4*)wrow;
    float4 wb = *(const float4*)(wrow + 4);
    float v8[8] = {wa.x, wa.y, wa.z, wa.w, wb.x, wb.y, wb.z, wb.w};
    bf16x8 whi, wlo;
    #pragma unroll
    for (int j = 0; j < 8; j++) {
      unsigned short h = f2bf(v8[j]);
      whi[j] = (short)h;
      wlo[j] = (short)f2bf(v8[j] - bf2f(h));
    }
    f32x4 aacc[2] = {};
    #pragma unroll
    for (int mt = 0; mt < 2; mt++) {
      int row = mh * 32 + mt * 16 + l15;
      bf16x8 ga = *(const bf16x8*)((char*)gs + k8 * 4096 + row * 64 +
                                   ((quad ^ ((row >> 1) & 3)) << 4));
      aacc[mt] = __builtin_amdgcn_mfma_f32_16x16x32_bf16(ga, whi, aacc[mt], 0, 0, 0);
      aacc[mt] = __builtin_amdgcn_mfma_f32_16x16x32_bf16(ga, wlo, aacc[mt], 0, 0, 0);
    }
    if (l15 < 8) {
      #pragma unroll
      for (int mt = 0; mt < 2; mt++)
        #pragma unroll
        for (int r = 0; r < 4; r++)
          prt[k8 * 512 + (mh * 32 + mt * 16 + quad * 4 + r) * 8 + l15] = aacc[mt][r];
    }
  }
  __syncthreads();   // partials complete

  // ---- one transcendental set per (row,w): 512 threads ----
  if (t < 512) {
    float s = 0.f;
    #pragma unroll
    for (int k = 0; k < 8; k++) s += prt[k * 512 + t];
    float th = (0.5f * PI_F) * fast_tanh(s + bpre[t & 7]);
    int row = t >> 3, w = t & 7;
    csw[row * 16 + w] = __cosf(th);
    csw[row * 16 + 8 + w] = __sinf(th);
  }
  __syncthreads();   // csw complete (partials consumed -> P0s region free)

  // ---- RY product state -> P0s panels; wave wv owns rows wv*4..+3 ----
  #pragma unroll
  for (int rr = 0; rr < 4; rr++) {
    int row = wv * 4 + rr;
    float4 c0 = *(const float4*)&csw[row * 16];
    float4 c1 = *(const float4*)&csw[row * 16 + 4];
    float4 s0 = *(const float4*)&csw[row * 16 + 8];
    float4 s1 = *(const float4*)&csw[row * 16 + 12];
    float cw[8] = {c0.x, c0.y, c0.z, c0.w, c1.x, c1.y, c1.z, c1.w};
    float sw[8] = {s0.x, s0.y, s0.z, s0.w, s1.x, s1.y, s1.z, s1.w};
    // amp index n = 4*lane + j : bits 0,1 = j ; bits 2..7 = lane bits 0..5
    float pl = 1.f;
    #pragma unroll
    for (int b = 0; b < 6; b++) pl *= ((lane >> b) & 1) ? sw[b + 2] : cw[b + 2];
    ushort4 o;
    o.x = f2bf(pl * cw[0] * cw[1]);
    o.y = f2bf(pl * sw[0] * cw[1]);
    o.z = f2bf(pl * cw[0] * sw[1]);
    o.w = f2bf(pl * sw[0] * sw[1]);
    int jj = lane & 7;
    int cswz = (jj >> 1) ^ ((row >> 1) & 3);
    *(ushort4*)((char*)P0s + (lane >> 3) * 4096 + row * 64 + cswz * 16 + (jj & 1) * 8) = o;
  }
  // hoist stage-B Uri fragment loads above the barrier (fly under the barrier wait)
  const unsigned short* Up = Uri + (size_t)(wv * 32 + l15) * 256 + quad * 8;
  bf16x8 ua[2][2];
  #pragma unroll
  for (int sl = 0; sl < 2; sl++)
    #pragma unroll
    for (int nt = 0; nt < 2; nt++)
      ua[sl][nt] = *(const bf16x8*)(Up + sl * 32 + nt * 4096);
  __syncthreads();   // P0s complete

  // ---- stage B: S = P0 @ Uri^T; wave wv owns T-col block wv (16 cols, re+im) ----
  // Uri interleaved: rows wv*32 + l15 (re), wv*32 + 16 + l15 (im).
  f32x4 acc1[4][2] = {};
  {
    #pragma unroll
    for (int k8 = 0; k8 < 8; k8++) {
      int cur = k8 & 1;
      #pragma unroll
      for (int mt = 0; mt < 4; mt++) {
        int row = mt * 16 + l15;
        bf16x8 pa = *(const bf16x8*)((char*)P0s + k8 * 4096 + row * 64 +
                                     ((quad ^ ((row >> 1) & 3)) << 4));
        acc1[mt][0] = __builtin_amdgcn_mfma_f32_16x16x32_bf16(pa, ua[cur][0], acc1[mt][0], 0, 0, 0);
        acc1[mt][1] = __builtin_amdgcn_mfma_f32_16x16x32_bf16(pa, ua[cur][1], acc1[mt][1], 0, 0, 0);
      }
      if (k8 < 6) {
        #pragma unroll
        for (int nt = 0; nt < 2; nt++)
          ua[cur][nt] = *(const bf16x8*)(Up + (k8 + 2) * 32 + nt * 4096);
      }
    }
  }

  // T = Sre^2 + Sim^2 -> Ts panels (reuses gs arena; same swizzle)
  {
    int colT = wv * 16 + l15;
    int kbc = colT >> 5, chunk = (colT >> 3) & 3, e = colT & 7;
    #pragma unroll
    for (int mt = 0; mt < 4; mt++) {
      #pragma unroll
      for (int r = 0; r < 4; r++) {
        int row = mt * 16 + quad * 4 + r;
        float tre = acc1[mt][0][r], tim = acc1[mt][1][r];
        *(_Float16*)((char*)Ts + kbc * 4096 + row * 64 +
                     ((chunk ^ ((row >> 1) & 3)) << 4) + e * 2)
            = (_Float16)(tre * tre + tim * tim);
      }
    }
  }
  // hoist stage-C Gt fragment loads above the barrier
  const _Float16* Gp = Gt + (size_t)(wv * 16 + l15) * 256 + quad * 8;
  f16x8 gf[2];
  gf[0] = *(const f16x8*)(Gp);
  gf[1] = *(const f16x8*)(Gp + 32);
  __syncthreads();   // Ts complete

  // ---- stage C: out = T @ Gt^T + bpost; wave wv owns out-cols wv*16..+15 ----
  f32x4 acc2[4] = {};
  {
    #pragma unroll
    for (int k8 = 0; k8 < 8; k8++) {
      int cur = k8 & 1;
      #pragma unroll
      for (int mt = 0; mt < 4; mt++) {
        int row = mt * 16 + l15;
        f16x8 tf = *(const f16x8*)((char*)Ts + k8 * 4096 + row * 64 +
                                   ((quad ^ ((row >> 1) & 3)) << 4));
        acc2[mt] = __builtin_amdgcn_mfma_f32_16x16x32_f16(tf, gf[cur], acc2[mt], 0, 0, 0);
      }
      if (k8 < 6) gf[cur] = *(const f16x8*)(Gp + (k8 + 2) * 32);
    }
  }

  // epilogue: bias + fp32 store with sample un-permute (s = i*16+b -> b*1024+i)
  {
    int col = wv * 16 + l15;
    float bp = bpost[col];
    #pragma unroll
    for (int mt = 0; mt < 4; mt++) {
      #pragma unroll
      for (int r = 0; r < 4; r++) {
        int row = mt * 16 + quad * 4 + r;
        int s = blockIdx.x * 64 + row;
        int orow = (s & 15) * 1024 + (s >> 4);
        out[(size_t)orow * 256 + col] = acc2[mt][r] + bp;
      }
    }
  }
}

// ---------------- host launch ----------------
extern "C" void kernel_launch(void* const* d_in, const int* in_sizes, int n_in,
                              void* d_out, int out_size, void* d_ws, size_t ws_size,
                              hipStream_t stream) {
  const float* x     = (const float*)d_in[0];  // (16,1024,256)
  const float* adj   = (const float*)d_in[1];  // (1024,1024)
  const float* Wg    = (const float*)d_in[2];  // (256,256)
  const float* bg    = (const float*)d_in[3];  // (256,)
  const float* Wpre  = (const float*)d_in[4];  // (8,256)
  const float* bpre  = (const float*)d_in[5];  // (8,)
  const float* qw    = (const float*)d_in[6];  // (2,8)
  const float* Wpost = (const float*)d_in[7];  // (256,8)
  const float* bpost = (const float*)d_in[8];  // (256,)
  float* out = (float*)d_out;                  // (16,1024,256)

  char* ws = (char*)d_ws;
  unsigned short* adj_bf  = (unsigned short*)(ws + 0);          // 2 MiB
  unsigned short* Wg_bf   = (unsigned short*)(ws + 2097152);    // 128 KiB
  unsigned short* xT_bf   = (unsigned short*)(ws + 2228224);    // 8 MiB  (4096 x 1024)
  unsigned short* xagg_bf = (unsigned short*)(ws + 10616832);   // 8 MiB  (16384 x 256 view)
  unsigned short* Uri     = (unsigned short*)(ws + 19005440);   // 256 KiB (512 x 256)
  _Float16*       Gt      = (_Float16*)(ws + 19267584);         // 128 KiB (256 x 256)

  // 1) prep: adj/Wg cvt + U-builder (interleaved) + G-builder + x transpose
  prep_kernel<<<5264, 256, 0, stream>>>(adj, adj_bf, Wg, Wg_bf, qw, Uri,
                                        Wpost, Gt, x, xT_bf);

  // 2) xagg = adj @ X'  (1024 x 4096 x 1024, tile 128x128, dbuf, XCD-chunked) -> bf16
  gemm1_kernel<<<256, 256, 0, stream>>>(adj_bf, xT_bf, xagg_bf, 1024, 32, 4096);

  // 3) fused: g-GEMM + GELU + MFMA-angles + P0 (LDS) + S-GEMM + |S|^2 + out-GEMM
  qfused_kernel<<<256, 1024, 0, stream>>>(xagg_bf, Wg_bf, bg, Wpre, bpre, Uri, Gt, bpost, out);
}

// Round 8
// 128.380 us; speedup vs baseline: 1.0389x; 1.0389x over previous
//
#include <hip/hip_runtime.h>
#include <math.h>

typedef __attribute__((ext_vector_type(8))) short bf16x8;
typedef _Float16 f16x8 __attribute__((ext_vector_type(8)));
typedef __attribute__((ext_vector_type(4))) float f32x4;

#define PI_F 3.14159265358979323846f

__device__ __forceinline__ unsigned short f2bf(float f) {
  unsigned int u = __float_as_uint(f);
  u += 0x7FFFu + ((u >> 16) & 1u);   // RNE to bf16
  return (unsigned short)(u >> 16);
}

__device__ __forceinline__ float bf2f(unsigned short u) {
  return __uint_as_float(((unsigned int)u) << 16);
}

__device__ __forceinline__ void async_ld16(const unsigned short* g, unsigned short* l) {
  __builtin_amdgcn_global_load_lds(
      (const __attribute__((address_space(1))) void*)g,
      (__attribute__((address_space(3))) void*)l,
      16, 0, 0);
}

// fast erf, A&S 7.1.26, |err| <= 1.5e-7 absolute
__device__ __forceinline__ float fast_erf(float x) {
  float a = fabsf(x);
  float t = 1.0f / fmaf(0.3275911f, a, 1.0f);
  float p = t * fmaf(t, fmaf(t, fmaf(t, fmaf(t, 1.061405429f, -1.453152027f),
                                     1.421413741f), -0.284496736f), 0.254829592f);
  float e = __expf(-a * a);
  float r = 1.0f - p * e;
  return copysignf(r, x);
}

__device__ __forceinline__ float fast_tanh(float a) {
  float e = __expf(2.0f * a);
  return 1.0f - 2.0f / (e + 1.0f);
}

// RX on stored basis: XOR-pair (lane-mask ML, register-mask MR); RX matrix symmetric.
template<int ML, int MR>
__device__ __forceinline__ void apply_rx(float re[4], float im[4], float c, float s) {
  float pr[4], pi[4];
  #pragma unroll
  for (int r = 0; r < 4; r++) {
    float vr = re[r ^ MR], vi = im[r ^ MR];
    if (ML) { vr = __shfl_xor(vr, ML, 64); vi = __shfl_xor(vi, ML, 64); }
    pr[r] = vr; pi[r] = vi;
  }
  #pragma unroll
  for (int r = 0; r < 4; r++) {
    re[r] = fmaf(c, re[r],  s * pi[r]);
    im[r] = fmaf(c, im[r], -s * pr[r]);
  }
}

// ---------------- prep: adj/Wg cvt, U-builder (interleaved), G-builder, x transpose ----
// blocks [0,1024): adj cvt; [1024,1088): Wg cvt; [1088,1152): U-builder;
// [1152,1168): G-builder; [1168,5264): x transpose (16,1024,256)->(4096,1024) bf16.
// Transpose vectorized (G13): float4 reads + ushort4 stores.
__global__ __launch_bounds__(256)
void prep_kernel(const float* __restrict__ adj, unsigned short* __restrict__ adj_bf,
                 const float* __restrict__ Wg, unsigned short* __restrict__ Wg_bf,
                 const float* __restrict__ qw, unsigned short* __restrict__ Uri,
                 const float* __restrict__ Wpost, _Float16* __restrict__ Gt,
                 const float* __restrict__ x, unsigned short* __restrict__ xT) {
  __shared__ float smem[1056];
  int bid = blockIdx.x, t = threadIdx.x;
  if (bid < 1024) {
    int i = bid * 256 + t;
    float4 v = ((const float4*)adj)[i];
    ushort4 o; o.x = f2bf(v.x); o.y = f2bf(v.y); o.z = f2bf(v.z); o.w = f2bf(v.w);
    ((ushort4*)adj_bf)[i] = o;
  } else if (bid < 1088) {
    int i = (bid - 1024) * 256 + t;
    float4 v = ((const float4*)Wg)[i];
    ushort4 o; o.x = f2bf(v.x); o.y = f2bf(v.y); o.z = f2bf(v.z); o.w = f2bf(v.w);
    ((ushort4*)Wg_bf)[i] = o;
  } else if (bid < 1152) {
    // U-builder: simulate entangler on basis k. CNOT rings deferred (linear maps);
    // layer-2 RX masks = R^-1 e_w; logical index n = R^2 s (rows of R^2 below).
    // Output layout INTERLEAVED by 16-blocks: row (n>>4)*32 + (n&15)      = Ure[n][*]
    //                                         row (n>>4)*32 + 16 + (n&15) = Uim[n][*]
    if (t < 16) { smem[t] = cosf(0.5f * qw[t]); smem[16 + t] = sinf(0.5f * qw[t]); }
    __syncthreads();
    int wv = t >> 6, L = t & 63;
    int k = (bid - 1088) * 4 + wv;
    float re[4], im[4];
    #pragma unroll
    for (int r = 0; r < 4; r++) { re[r] = (r * 64 + L == k) ? 1.f : 0.f; im[r] = 0.f; }
    // layer 1 RX (F = I)
    apply_rx<1, 0>(re, im, smem[0], smem[16]);
    apply_rx<2, 0>(re, im, smem[1], smem[17]);
    apply_rx<4, 0>(re, im, smem[2], smem[18]);
    apply_rx<8, 0>(re, im, smem[3], smem[19]);
    apply_rx<16, 0>(re, im, smem[4], smem[20]);
    apply_rx<32, 0>(re, im, smem[5], smem[21]);
    apply_rx<0, 1>(re, im, smem[6], smem[22]);
    apply_rx<0, 2>(re, im, smem[7], smem[23]);
    // layer 2 RX (F = R): masks R^-1 e_w
    apply_rx<3, 0>(re, im, smem[8], smem[24]);
    apply_rx<6, 0>(re, im, smem[9], smem[25]);
    apply_rx<12, 0>(re, im, smem[10], smem[26]);
    apply_rx<24, 0>(re, im, smem[11], smem[27]);
    apply_rx<48, 0>(re, im, smem[12], smem[28]);
    apply_rx<32, 1>(re, im, smem[13], smem[29]);
    apply_rx<0, 3>(re, im, smem[14], smem[30]);
    apply_rx<3, 2>(re, im, smem[15], smem[31]);
    const int M[8] = {0xAB, 0xFD, 0xFA, 0xF5, 0xEA, 0xD5, 0xAA, 0x55};
    #pragma unroll
    for (int r = 0; r < 4; r++) {
      int n = 0;
      #pragma unroll
      for (int w = 0; w < 8; w++) {
        int bit = (__popc(L & (M[w] & 63)) ^ __popc((r << 6) & M[w])) & 1;
        n |= bit << w;
      }
      int row_re = ((n >> 4) << 5) + (n & 15);
      Uri[(size_t)row_re * 256 + k] = f2bf(re[r]);
      Uri[(size_t)(row_re + 16) * 256 + k] = f2bf(im[r]);
    }
  } else if (bid < 1168) {
    // G-builder: Gt[h][n] = sum_w (-1)^{bit_w(n)} Wpost[h][w]  (f16)
    int tid = (bid - 1152) * 256 + t;   // [0,4096)
    int h = tid >> 4;
    int n0 = (tid & 15) << 4;
    float wv8[8];
    #pragma unroll
    for (int w = 0; w < 8; w++) wv8[w] = Wpost[h * 8 + w];
    #pragma unroll
    for (int j = 0; j < 16; j++) {
      int n = n0 + j;
      float sum = 0.f;
      #pragma unroll
      for (int w = 0; w < 8; w++) sum += ((n >> w) & 1) ? -wv8[w] : wv8[w];
      Gt[h * 256 + n] = (_Float16)sum;
    }
  } else {
    // x transpose, vectorized: 32x32 tile; float4 read, ushort4 write.
    int tb = bid - 1168;
    int jt = tb & 31, ht = (tb >> 5) & 7, bb = tb >> 8;
    const float* xb = x + (size_t)bb * 1024 * 256;
    int row = t >> 3, cg = t & 7;        // row 0..31, col-group 0..7 (4 cols each)
    {
      float4 v = *(const float4*)&xb[(size_t)(jt * 32 + row) * 256 + ht * 32 + cg * 4];
      smem[row * 33 + cg * 4 + 0] = v.x;
      smem[row * 33 + cg * 4 + 1] = v.y;
      smem[row * 33 + cg * 4 + 2] = v.z;
      smem[row * 33 + cg * 4 + 3] = v.w;
    }
    __syncthreads();
    unsigned short* xTb = xT + (size_t)bb * 256 * 1024;
    int h = ht * 32 + row;
    ushort4 o;
    o.x = f2bf(smem[(cg * 4 + 0) * 33 + row]);
    o.y = f2bf(smem[(cg * 4 + 1) * 33 + row]);
    o.z = f2bf(smem[(cg * 4 + 2) * 33 + row]);
    o.w = f2bf(smem[(cg * 4 + 3) * 33 + row]);
    *(ushort4*)&xTb[(size_t)h * 1024 + jt * 32 + cg * 4] = o;
  }
}

// ---------------- gemm1: C = A * Bt^T, tile 128(M) x 128(N), BK=64, DOUBLE-BUFFERED ----
// 256 blocks x 1024 thr (16 waves, 4x4 grid, 32x32 out/wave) -> 1 block/CU but
// 4 waves/SIMD (R7's regression was 256-thr blocks here: 1 wave/SIMD, no hiding).
// Staged traffic 512 KB/CU (vs R6's 768). Dbuf issue-before-compute; single barrier
// per K-step. XCD-chunked swizzle (256 % 8 == 0, bijective). LDS chunks XOR-swizzled
// via pre-swizzled GLOBAL source (global_load_lds dest stays linear).
__global__ __launch_bounds__(1024)
void gemm1_kernel(const unsigned short* __restrict__ A,
                  const unsigned short* __restrict__ Bt,
                  unsigned short* __restrict__ C,
                  int K, int tilesN, int ldC) {
  __shared__ unsigned short Ss[2 * 2 * 2 * 128 * 32];   // 64 KB [buf][mat][kb][128][32]
  int bid = blockIdx.x;
  int swz = (bid & 7) * 32 + (bid >> 3);   // XCD-chunked
  int in_ = swz >> 3;    // 0..31  N-tile (128 cols)
  int im  = swz & 7;     // 0..7   M-tile (128 rows)
  const unsigned short* Ab  = A  + (long long)im * 128 * K;
  const unsigned short* Btb = Bt + (long long)in_ * 128 * K;

  int t = threadIdx.x;
  int wv = t >> 6, lane = t & 63;
  int wm = wv >> 2, wn = wv & 3;           // 4x4 wave grid, 32x32 out each
  int l15 = lane & 15, quad = lane >> 4;

  // staging: 2048 slots/step (16B each) = 2 insts/thread (one per kb).
  // thread t -> matrix isB = t>>9, slot s0 = t&511; row r0 = s0>>2, swz chunk c0.
  int isB = t >> 9;
  int s0  = t & 511;
  int r0  = s0 >> 2, c0 = (s0 & 3) ^ ((r0 >> 1) & 3);
  const unsigned short* Gb = isB ? Btb : Ab;
  long long go = (long long)r0 * K + c0 * 8;

  f32x4 acc[2][2] = {};

  // prologue: stage buf0 @ kk=0
  #pragma unroll
  for (int kb = 0; kb < 2; kb++)
    async_ld16(Gb + go + kb * 32, &Ss[(isB * 2 + kb) * 4096 + s0 * 8]);
  __syncthreads();

  int nk = K >> 6;   // 16
  for (int ki = 0; ki < nk; ki++) {
    int buf = ki & 1;
    if (ki + 1 < nk) {           // issue next tile's loads BEFORE compute
      int nb = buf ^ 1;
      long long kk = (long long)(ki + 1) << 6;
      #pragma unroll
      for (int kb = 0; kb < 2; kb++)
        async_ld16(Gb + go + kk + kb * 32,
                   &Ss[((nb * 2 + isB) * 2 + kb) * 4096 + s0 * 8]);
    }
    #pragma unroll
    for (int kb = 0; kb < 2; kb++) {
      const unsigned short* Sa = &Ss[((buf * 2 + 0) * 2 + kb) * 4096];
      const unsigned short* Sb = &Ss[((buf * 2 + 1) * 2 + kb) * 4096];
      bf16x8 af[2], bfr[2];
      #pragma unroll
      for (int mt = 0; mt < 2; mt++) {
        int row = wm * 32 + mt * 16 + l15;
        af[mt] = *(const bf16x8*)&Sa[row * 32 + ((quad ^ ((row >> 1) & 3)) * 8)];
      }
      #pragma unroll
      for (int nt = 0; nt < 2; nt++) {
        int row = wn * 32 + nt * 16 + l15;
        bfr[nt] = *(const bf16x8*)&Sb[row * 32 + ((quad ^ ((row >> 1) & 3)) * 8)];
      }
      #pragma unroll
      for (int mt = 0; mt < 2; mt++)
        #pragma unroll
        for (int nt = 0; nt < 2; nt++)
          acc[mt][nt] = __builtin_amdgcn_mfma_f32_16x16x32_bf16(af[mt], bfr[nt], acc[mt][nt], 0, 0, 0);
    }
    __syncthreads();   // drains this step's prefetch (overlapped with the MFMAs above)
  }

  int n0 = in_ * 128;
  #pragma unroll
  for (int mt = 0; mt < 2; mt++) {
    #pragma unroll
    for (int nt = 0; nt < 2; nt++) {
      int colg = n0 + wn * 32 + nt * 16 + l15;
      #pragma unroll
      for (int r = 0; r < 4; r++) {
        int rowg = im * 128 + wm * 32 + mt * 16 + quad * 4 + r;
        C[(size_t)rowg * ldC + colg] = f2bf(acc[mt][nt][r]);
      }
    }
  }
}

// ---------------- qfused: g-GEMM + GELU + MFMA-angles + P0 + S-GEMM + |S|^2 + out-GEMM ----
// 256 blocks x 1024 thr (16 waves); block owns 64 samples. 1 block/CU, 4 waves/SIMD.
// Barrier-shadow loads: all 8 Wg frags preloaded above the As DMA barrier (fly under
// the HBM wait); first Uri frags hoisted above the P0s barrier; Gt frags above the Ts
// barrier. Same loads, same consumption order -> bit-identical numerics.
// LDS 100 KB: As 32K | gs|Ts 32K | P0s(prt) 32K | csw 4K
__global__ __launch_bounds__(1024, 4)
void qfused_kernel(const unsigned short* __restrict__ xagg,
                   const unsigned short* __restrict__ Wg,
                   const float* __restrict__ bg,
                   const float* __restrict__ Wpre, const float* __restrict__ bpre,
                   const unsigned short* __restrict__ Uri,
                   const _Float16* __restrict__ Gt,
                   const float* __restrict__ bpost,
                   float* __restrict__ out) {
  __shared__ __align__(16) char smemraw[102400];
  unsigned short* As  = (unsigned short*)smemraw;            // 32 KB swz panels [8][64][32] bf16
  unsigned short* gs  = (unsigned short*)(smemraw + 32768);  // 32 KB swz panels [8][64][32] bf16
  _Float16*       Ts  = (_Float16*)(smemraw + 32768);        //   (reused: f16 T panels, same swz)
  unsigned short* P0s = (unsigned short*)(smemraw + 65536);  // 32 KB swz panels
  float*          prt = (float*)(smemraw + 65536);           //   (early reuse: [8][64][8] f32 partials)
  float*          csw = (float*)(smemraw + 98304);           // 4 KB [64][16]: cw[8] | sw[8] per row

  int t = threadIdx.x;
  int wv = t >> 6, lane = t & 63;
  int l15 = lane & 15, quad = lane >> 4;

  const unsigned short* Ab = xagg + (size_t)blockIdx.x * 64 * 256;

  // ---- stage xagg A-tile (64x256) into LDS ONCE (issue), then preload ALL Wg
  //      fragments for this wave's columns so they fly under the DMA wait ----
  #pragma unroll
  for (int q = 0; q < 2; q++) {
    int sidx = q * 1024 + t;           // 0..2047 slots of 16B
    int kb = sidx >> 8;                // k-panel 0..7
    int r  = (sidx >> 2) & 63;         // row 0..63
    int c  = (sidx & 3) ^ ((r >> 1) & 3);
    async_ld16(Ab + (size_t)r * 256 + kb * 32 + c * 8, &As[sidx * 8]);
  }
  const unsigned short* Wp = Wg + (size_t)(wv * 16 + l15) * 256 + quad * 8;
  bf16x8 wf[8];
  #pragma unroll
  for (int k8 = 0; k8 < 8; k8++) wf[k8] = *(const bf16x8*)(Wp + k8 * 32);
  __syncthreads();   // As ready (Wg frags arrived during the same drain)

  // ---- stage A: g = GELU(xagg @ Wg^T + bg); wave wv owns cols wv*16..+15 ----
  f32x4 acc[4] = {};
  #pragma unroll
  for (int k8 = 0; k8 < 8; k8++) {
    #pragma unroll
    for (int mt = 0; mt < 4; mt++) {
      int row = mt * 16 + l15;
      bf16x8 af = *(const bf16x8*)&As[k8 * 2048 + row * 32 + ((quad ^ ((row >> 1) & 3)) * 8)];
      acc[mt] = __builtin_amdgcn_mfma_f32_16x16x32_bf16(af, wf[k8], acc[mt], 0, 0, 0);
    }
  }
  {
    int col = wv * 16 + l15;
    float bgl = bg[col];
    int kbc = col >> 5, chunk = (col >> 3) & 3, e = col & 7;
    #pragma unroll
    for (int mt = 0; mt < 4; mt++) {
      #pragma unroll
      for (int r = 0; r < 4; r++) {
        int row = mt * 16 + quad * 4 + r;
        float v = acc[mt][r] + bgl;
        v = 0.5f * v * (1.0f + fast_erf(v * 0.7071067811865475f));
        *(unsigned short*)((char*)gs + kbc * 4096 + row * 64 +
                           ((chunk ^ ((row >> 1) & 3)) << 4) + e * 2) = f2bf(v);
      }
    }
  }
  __syncthreads();   // gs complete

  // ---- angle GEMM: ang = g @ Wpre^T; wave pair (k8 = wv>>1) x M-half (mh = wv&1) ----
  {
    int k8 = wv >> 1, mh = wv & 1;
    const float* wrow = Wpre + (size_t)(l15 & 7) * 256 + k8 * 32 + quad * 8;
    float4 wa = *(const float4*)wrow;
    float4 wb = *(const float4*)(wrow + 4);
    float v8[8] = {wa.x, wa.y, wa.z, wa.w, wb.x, wb.y, wb.z, wb.w};
    bf16x8 whi, wlo;
    #pragma unroll
    for (int j = 0; j < 8; j++) {
      unsigned short h = f2bf(v8[j]);
      whi[j] = (short)h;
      wlo[j] = (short)f2bf(v8[j] - bf2f(h));
    }
    f32x4 aacc[2] = {};
    #pragma unroll
    for (int mt = 0; mt < 2; mt++) {
      int row = mh * 32 + mt * 16 + l15;
      bf16x8 ga = *(const bf16x8*)((char*)gs + k8 * 4096 + row * 64 +
                                   ((quad ^ ((row >> 1) & 3)) << 4));
      aacc[mt] = __builtin_amdgcn_mfma_f32_16x16x32_bf16(ga, whi, aacc[mt], 0, 0, 0);
      aacc[mt] = __builtin_amdgcn_mfma_f32_16x16x32_bf16(ga, wlo, aacc[mt], 0, 0, 0);
    }
    if (l15 < 8) {
      #pragma unroll
      for (int mt = 0; mt < 2; mt++)
        #pragma unroll
        for (int r = 0; r < 4; r++)
          prt[k8 * 512 + (mh * 32 + mt * 16 + quad * 4 + r) * 8 + l15] = aacc[mt][r];
    }
  }
  __syncthreads();   // partials complete

  // ---- one transcendental set per (row,w): 512 threads ----
  if (t < 512) {
    float s = 0.f;
    #pragma unroll
    for (int k = 0; k < 8; k++) s += prt[k * 512 + t];
    float th = (0.5f * PI_F) * fast_tanh(s + bpre[t & 7]);
    int row = t >> 3, w = t & 7;
    csw[row * 16 + w] = __cosf(th);
    csw[row * 16 + 8 + w] = __sinf(th);
  }
  __syncthreads();   // csw complete (partials consumed -> P0s region free)

  // ---- RY product state -> P0s panels; wave wv owns rows wv*4..+3 ----
  #pragma unroll
  for (int rr = 0; rr < 4; rr++) {
    int row = wv * 4 + rr;
    float4 c0 = *(const float4*)&csw[row * 16];
    float4 c1 = *(const float4*)&csw[row * 16 + 4];
    float4 s0 = *(const float4*)&csw[row * 16 + 8];
    float4 s1 = *(const float4*)&csw[row * 16 + 12];
    float cw[8] = {c0.x, c0.y, c0.z, c0.w, c1.x, c1.y, c1.z, c1.w};
    float sw[8] = {s0.x, s0.y, s0.z, s0.w, s1.x, s1.y, s1.z, s1.w};
    // amp index n = 4*lane + j : bits 0,1 = j ; bits 2..7 = lane bits 0..5
    float pl = 1.f;
    #pragma unroll
    for (int b = 0; b < 6; b++) pl *= ((lane >> b) & 1) ? sw[b + 2] : cw[b + 2];
    ushort4 o;
    o.x = f2bf(pl * cw[0] * cw[1]);
    o.y = f2bf(pl * sw[0] * cw[1]);
    o.z = f2bf(pl * cw[0] * sw[1]);
    o.w = f2bf(pl * sw[0] * sw[1]);
    int jj = lane & 7;
    int cswz = (jj >> 1) ^ ((row >> 1) & 3);
    *(ushort4*)((char*)P0s + (lane >> 3) * 4096 + row * 64 + cswz * 16 + (jj & 1) * 8) = o;
  }
  // hoist stage-B Uri fragment loads above the barrier (fly under the barrier wait)
  const unsigned short* Up = Uri + (size_t)(wv * 32 + l15) * 256 + quad * 8;
  bf16x8 ua[2][2];
  #pragma unroll
  for (int sl = 0; sl < 2; sl++)
    #pragma unroll
    for (int nt = 0; nt < 2; nt++)
      ua[sl][nt] = *(const bf16x8*)(Up + sl * 32 + nt * 4096);
  __syncthreads();   // P0s complete

  // ---- stage B: S = P0 @ Uri^T; wave wv owns T-col block wv (16 cols, re+im) ----
  // Uri interleaved: rows wv*32 + l15 (re), wv*32 + 16 + l15 (im).
  f32x4 acc1[4][2] = {};
  {
    #pragma unroll
    for (int k8 = 0; k8 < 8; k8++) {
      int cur = k8 & 1;
      #pragma unroll
      for (int mt = 0; mt < 4; mt++) {
        int row = mt * 16 + l15;
        bf16x8 pa = *(const bf16x8*)((char*)P0s + k8 * 4096 + row * 64 +
                                     ((quad ^ ((row >> 1) & 3)) << 4));
        acc1[mt][0] = __builtin_amdgcn_mfma_f32_16x16x32_bf16(pa, ua[cur][0], acc1[mt][0], 0, 0, 0);
        acc1[mt][1] = __builtin_amdgcn_mfma_f32_16x16x32_bf16(pa, ua[cur][1], acc1[mt][1], 0, 0, 0);
      }
      if (k8 < 6) {
        #pragma unroll
        for (int nt = 0; nt < 2; nt++)
          ua[cur][nt] = *(const bf16x8*)(Up + (k8 + 2) * 32 + nt * 4096);
      }
    }
  }

  // T = Sre^2 + Sim^2 -> Ts panels (reuses gs arena; same swizzle)
  {
    int colT = wv * 16 + l15;
    int kbc = colT >> 5, chunk = (colT >> 3) & 3, e = colT & 7;
    #pragma unroll
    for (int mt = 0; mt < 4; mt++) {
      #pragma unroll
      for (int r = 0; r < 4; r++) {
        int row = mt * 16 + quad * 4 + r;
        float tre = acc1[mt][0][r], tim = acc1[mt][1][r];
        *(_Float16*)((char*)Ts + kbc * 4096 + row * 64 +
                     ((chunk ^ ((row >> 1) & 3)) << 4) + e * 2)
            = (_Float16)(tre * tre + tim * tim);
      }
    }
  }
  // hoist stage-C Gt fragment loads above the barrier
  const _Float16* Gp = Gt + (size_t)(wv * 16 + l15) * 256 + quad * 8;
  f16x8 gf[2];
  gf[0] = *(const f16x8*)(Gp);
  gf[1] = *(const f16x8*)(Gp + 32);
  __syncthreads();   // Ts complete

  // ---- stage C: out = T @ Gt^T + bpost; wave wv owns out-cols wv*16..+15 ----
  f32x4 acc2[4] = {};
  {
    #pragma unroll
    for (int k8 = 0; k8 < 8; k8++) {
      int cur = k8 & 1;
      #pragma unroll
      for (int mt = 0; mt < 4; mt++) {
        int row = mt * 16 + l15;
        f16x8 tf = *(const f16x8*)((char*)Ts + k8 * 4096 + row * 64 +
                                   ((quad ^ ((row >> 1) & 3)) << 4));
        acc2[mt] = __builtin_amdgcn_mfma_f32_16x16x32_f16(tf, gf[cur], acc2[mt], 0, 0, 0);
      }
      if (k8 < 6) gf[cur] = *(const f16x8*)(Gp + (k8 + 2) * 32);
    }
  }

  // epilogue: bias + fp32 store with sample un-permute (s = i*16+b -> b*1024+i)
  {
    int col = wv * 16 + l15;
    float bp = bpost[col];
    #pragma unroll
    for (int mt = 0; mt < 4; mt++) {
      #pragma unroll
      for (int r = 0; r < 4; r++) {
        int row = mt * 16 + quad * 4 + r;
        int s = blockIdx.x * 64 + row;
        int orow = (s & 15) * 1024 + (s >> 4);
        out[(size_t)orow * 256 + col] = acc2[mt][r] + bp;
      }
    }
  }
}

// ---------------- host launch ----------------
extern "C" void kernel_launch(void* const* d_in, const int* in_sizes, int n_in,
                              void* d_out, int out_size, void* d_ws, size_t ws_size,
                              hipStream_t stream) {
  const float* x     = (const float*)d_in[0];  // (16,1024,256)
  const float* adj   = (const float*)d_in[1];  // (1024,1024)
  const float* Wg    = (const float*)d_in[2];  // (256,256)
  const float* bg    = (const float*)d_in[3];  // (256,)
  const float* Wpre  = (const float*)d_in[4];  // (8,256)
  const float* bpre  = (const float*)d_in[5];  // (8,)
  const float* qw    = (const float*)d_in[6];  // (2,8)
  const float* Wpost = (const float*)d_in[7];  // (256,8)
  const float* bpost = (const float*)d_in[8];  // (256,)
  float* out = (float*)d_out;                  // (16,1024,256)

  char* ws = (char*)d_ws;
  unsigned short* adj_bf  = (unsigned short*)(ws + 0);          // 2 MiB
  unsigned short* Wg_bf   = (unsigned short*)(ws + 2097152);    // 128 KiB
  unsigned short* xT_bf   = (unsigned short*)(ws + 2228224);    // 8 MiB  (4096 x 1024)
  unsigned short* xagg_bf = (unsigned short*)(ws + 10616832);   // 8 MiB  (16384 x 256 view)
  unsigned short* Uri     = (unsigned short*)(ws + 19005440);   // 256 KiB (512 x 256)
  _Float16*       Gt      = (_Float16*)(ws + 19267584);         // 128 KiB (256 x 256)

  // 1) prep: adj/Wg cvt + U-builder (interleaved) + G-builder + x transpose
  prep_kernel<<<5264, 256, 0, stream>>>(adj, adj_bf, Wg, Wg_bf, qw, Uri,
                                        Wpost, Gt, x, xT_bf);

  // 2) xagg = adj @ X'  (1024 x 4096 x 1024, tile 128x128, 16 waves, dbuf) -> bf16
  gemm1_kernel<<<256, 1024, 0, stream>>>(adj_bf, xT_bf, xagg_bf, 1024, 32, 4096);

  // 3) fused: g-GEMM + GELU + MFMA-angles + P0 (LDS) + S-GEMM + |S|^2 + out-GEMM
  qfused_kernel<<<256, 1024, 0, stream>>>(xagg_bf, Wg_bf, bg, Wpre, bpre, Uri, Gt, bpost, out);
}

// Round 9
// 125.446 us; speedup vs baseline: 1.0632x; 1.0234x over previous
//
#include <hip/hip_runtime.h>
#include <math.h>

typedef __attribute__((ext_vector_type(8))) short bf16x8;
typedef _Float16 f16x8 __attribute__((ext_vector_type(8)));
typedef __attribute__((ext_vector_type(4))) float f32x4;

#define PI_F 3.14159265358979323846f

__device__ __forceinline__ unsigned short f2bf(float f) {
  unsigned int u = __float_as_uint(f);
  u += 0x7FFFu + ((u >> 16) & 1u);   // RNE to bf16
  return (unsigned short)(u >> 16);
}

__device__ __forceinline__ float bf2f(unsigned short u) {
  return __uint_as_float(((unsigned int)u) << 16);
}

__device__ __forceinline__ void async_ld16(const unsigned short* g, unsigned short* l) {
  __builtin_amdgcn_global_load_lds(
      (const __attribute__((address_space(1))) void*)g,
      (__attribute__((address_space(3))) void*)l,
      16, 0, 0);
}

// fast erf, A&S 7.1.26, |err| <= 1.5e-7 absolute
__device__ __forceinline__ float fast_erf(float x) {
  float a = fabsf(x);
  float t = 1.0f / fmaf(0.3275911f, a, 1.0f);
  float p = t * fmaf(t, fmaf(t, fmaf(t, fmaf(t, 1.061405429f, -1.453152027f),
                                     1.421413741f), -0.284496736f), 0.254829592f);
  float e = __expf(-a * a);
  float r = 1.0f - p * e;
  return copysignf(r, x);
}

__device__ __forceinline__ float fast_tanh(float a) {
  float e = __expf(2.0f * a);
  return 1.0f - 2.0f / (e + 1.0f);
}

// RX on stored basis: XOR-pair (lane-mask ML, register-mask MR); RX matrix symmetric.
template<int ML, int MR>
__device__ __forceinline__ void apply_rx(float re[4], float im[4], float c, float s) {
  float pr[4], pi[4];
  #pragma unroll
  for (int r = 0; r < 4; r++) {
    float vr = re[r ^ MR], vi = im[r ^ MR];
    if (ML) { vr = __shfl_xor(vr, ML, 64); vi = __shfl_xor(vi, ML, 64); }
    pr[r] = vr; pi[r] = vi;
  }
  #pragma unroll
  for (int r = 0; r < 4; r++) {
    re[r] = fmaf(c, re[r],  s * pi[r]);
    im[r] = fmaf(c, im[r], -s * pr[r]);
  }
}

// ---------------- prep: adj/Wg cvt, U-builder (interleaved), G-builder, x transpose ----
// blocks [0,1024): adj cvt; [1024,1088): Wg cvt; [1088,1152): U-builder;
// [1152,1168): G-builder; [1168,5264): x transpose (16,1024,256)->(4096,1024) bf16.
// Transpose vectorized (G13): float4 reads + ushort4 stores.
__global__ __launch_bounds__(256)
void prep_kernel(const float* __restrict__ adj, unsigned short* __restrict__ adj_bf,
                 const float* __restrict__ Wg, unsigned short* __restrict__ Wg_bf,
                 const float* __restrict__ qw, unsigned short* __restrict__ Uri,
                 const float* __restrict__ Wpost, _Float16* __restrict__ Gt,
                 const float* __restrict__ x, unsigned short* __restrict__ xT) {
  __shared__ float smem[1056];
  int bid = blockIdx.x, t = threadIdx.x;
  if (bid < 1024) {
    int i = bid * 256 + t;
    float4 v = ((const float4*)adj)[i];
    ushort4 o; o.x = f2bf(v.x); o.y = f2bf(v.y); o.z = f2bf(v.z); o.w = f2bf(v.w);
    ((ushort4*)adj_bf)[i] = o;
  } else if (bid < 1088) {
    int i = (bid - 1024) * 256 + t;
    float4 v = ((const float4*)Wg)[i];
    ushort4 o; o.x = f2bf(v.x); o.y = f2bf(v.y); o.z = f2bf(v.z); o.w = f2bf(v.w);
    ((ushort4*)Wg_bf)[i] = o;
  } else if (bid < 1152) {
    // U-builder: simulate entangler on basis k. CNOT rings deferred (linear maps);
    // layer-2 RX masks = R^-1 e_w; logical index n = R^2 s (rows of R^2 below).
    // Output layout INTERLEAVED by 16-blocks: row (n>>4)*32 + (n&15)      = Ure[n][*]
    //                                         row (n>>4)*32 + 16 + (n&15) = Uim[n][*]
    if (t < 16) { smem[t] = cosf(0.5f * qw[t]); smem[16 + t] = sinf(0.5f * qw[t]); }
    __syncthreads();
    int wv = t >> 6, L = t & 63;
    int k = (bid - 1088) * 4 + wv;
    float re[4], im[4];
    #pragma unroll
    for (int r = 0; r < 4; r++) { re[r] = (r * 64 + L == k) ? 1.f : 0.f; im[r] = 0.f; }
    // layer 1 RX (F = I)
    apply_rx<1, 0>(re, im, smem[0], smem[16]);
    apply_rx<2, 0>(re, im, smem[1], smem[17]);
    apply_rx<4, 0>(re, im, smem[2], smem[18]);
    apply_rx<8, 0>(re, im, smem[3], smem[19]);
    apply_rx<16, 0>(re, im, smem[4], smem[20]);
    apply_rx<32, 0>(re, im, smem[5], smem[21]);
    apply_rx<0, 1>(re, im, smem[6], smem[22]);
    apply_rx<0, 2>(re, im, smem[7], smem[23]);
    // layer 2 RX (F = R): masks R^-1 e_w
    apply_rx<3, 0>(re, im, smem[8], smem[24]);
    apply_rx<6, 0>(re, im, smem[9], smem[25]);
    apply_rx<12, 0>(re, im, smem[10], smem[26]);
    apply_rx<24, 0>(re, im, smem[11], smem[27]);
    apply_rx<48, 0>(re, im, smem[12], smem[28]);
    apply_rx<32, 1>(re, im, smem[13], smem[29]);
    apply_rx<0, 3>(re, im, smem[14], smem[30]);
    apply_rx<3, 2>(re, im, smem[15], smem[31]);
    const int M[8] = {0xAB, 0xFD, 0xFA, 0xF5, 0xEA, 0xD5, 0xAA, 0x55};
    #pragma unroll
    for (int r = 0; r < 4; r++) {
      int n = 0;
      #pragma unroll
      for (int w = 0; w < 8; w++) {
        int bit = (__popc(L & (M[w] & 63)) ^ __popc((r << 6) & M[w])) & 1;
        n |= bit << w;
      }
      int row_re = ((n >> 4) << 5) + (n & 15);
      Uri[(size_t)row_re * 256 + k] = f2bf(re[r]);
      Uri[(size_t)(row_re + 16) * 256 + k] = f2bf(im[r]);
    }
  } else if (bid < 1168) {
    // G-builder: Gt[h][n] = sum_w (-1)^{bit_w(n)} Wpost[h][w]  (f16)
    int tid = (bid - 1152) * 256 + t;   // [0,4096)
    int h = tid >> 4;
    int n0 = (tid & 15) << 4;
    float wv8[8];
    #pragma unroll
    for (int w = 0; w < 8; w++) wv8[w] = Wpost[h * 8 + w];
    #pragma unroll
    for (int j = 0; j < 16; j++) {
      int n = n0 + j;
      float sum = 0.f;
      #pragma unroll
      for (int w = 0; w < 8; w++) sum += ((n >> w) & 1) ? -wv8[w] : wv8[w];
      Gt[h * 256 + n] = (_Float16)sum;
    }
  } else {
    // x transpose, vectorized: 32x32 tile; float4 read, ushort4 write.
    int tb = bid - 1168;
    int jt = tb & 31, ht = (tb >> 5) & 7, bb = tb >> 8;
    const float* xb = x + (size_t)bb * 1024 * 256;
    int row = t >> 3, cg = t & 7;        // row 0..31, col-group 0..7 (4 cols each)
    {
      float4 v = *(const float4*)&xb[(size_t)(jt * 32 + row) * 256 + ht * 32 + cg * 4];
      smem[row * 33 + cg * 4 + 0] = v.x;
      smem[row * 33 + cg * 4 + 1] = v.y;
      smem[row * 33 + cg * 4 + 2] = v.z;
      smem[row * 33 + cg * 4 + 3] = v.w;
    }
    __syncthreads();
    unsigned short* xTb = xT + (size_t)bb * 256 * 1024;
    int h = ht * 32 + row;
    ushort4 o;
    o.x = f2bf(smem[(cg * 4 + 0) * 33 + row]);
    o.y = f2bf(smem[(cg * 4 + 1) * 33 + row]);
    o.z = f2bf(smem[(cg * 4 + 2) * 33 + row]);
    o.w = f2bf(smem[(cg * 4 + 3) * 33 + row]);
    *(ushort4*)&xTb[(size_t)h * 1024 + jt * 32 + cg * 4] = o;
  }
}

// ---------------- gemm1: C = A * Bt^T, tile 128(M) x 128(N), BK=128, DOUBLE-BUFFERED ----
// 256 blocks x 1024 thr (16 waves, 4x4 grid, 32x32 out/wave). 1 block/CU (grid-bound)
// so barriers can't overlap with another block -> halve their count: BK=128 gives 8
// K-steps instead of 16, 2x staging amortization per barrier, 2x compute window over
// each in-flight load set. LDS 128 KB dbuf (we're 1 block/CU regardless; m132's
// occupancy objection doesn't apply). Same per-kb layout/swizzle and ascending-k MFMA
// order as BK=64 -> bit-identical numerics. XCD-chunked block swizzle.
__global__ __launch_bounds__(1024)
void gemm1_kernel(const unsigned short* __restrict__ A,
                  const unsigned short* __restrict__ Bt,
                  unsigned short* __restrict__ C,
                  int K, int tilesN, int ldC) {
  __shared__ unsigned short Ss[2 * 2 * 4 * 128 * 32];   // 128 KB [buf][mat][kb4][128][32]
  int bid = blockIdx.x;
  int swz = (bid & 7) * 32 + (bid >> 3);   // XCD-chunked (256 % 8 == 0, bijective)
  int in_ = swz >> 3;    // 0..31  N-tile (128 cols)
  int im  = swz & 7;     // 0..7   M-tile (128 rows)
  const unsigned short* Ab  = A  + (long long)im * 128 * K;
  const unsigned short* Btb = Bt + (long long)in_ * 128 * K;

  int t = threadIdx.x;
  int wv = t >> 6, lane = t & 63;
  int wm = wv >> 2, wn = wv & 3;           // 4x4 wave grid, 32x32 out each
  int l15 = lane & 15, quad = lane >> 4;

  // staging: 4096 slots/step (16B each) = 4 insts/thread (one per kb-panel).
  // thread t -> matrix isB = t>>9, local slot sl = t&511: row r = sl>>2, swz chunk c.
  int isB = t >> 9;
  int sl  = t & 511;
  int r0  = sl >> 2, c0 = (sl & 3) ^ ((r0 >> 1) & 3);
  const unsigned short* Gb = isB ? Btb : Ab;
  long long go = (long long)r0 * K + c0 * 8;

  f32x4 acc[2][2] = {};

  // prologue: stage buf0 @ kk=0
  #pragma unroll
  for (int kb = 0; kb < 4; kb++)
    async_ld16(Gb + go + kb * 32, &Ss[(isB * 4 + kb) * 4096 + sl * 8]);
  __syncthreads();

  int nk = K >> 7;   // 8
  for (int ki = 0; ki < nk; ki++) {
    int buf = ki & 1;
    if (ki + 1 < nk) {           // issue next tile's loads BEFORE compute
      int nb = buf ^ 1;
      long long kk = (long long)(ki + 1) << 7;
      #pragma unroll
      for (int kb = 0; kb < 4; kb++)
        async_ld16(Gb + go + kk + kb * 32,
                   &Ss[((nb * 2 + isB) * 4 + kb) * 4096 + sl * 8]);
    }
    #pragma unroll
    for (int kb = 0; kb < 4; kb++) {
      const unsigned short* Sa = &Ss[((buf * 2 + 0) * 4 + kb) * 4096];
      const unsigned short* Sb = &Ss[((buf * 2 + 1) * 4 + kb) * 4096];
      bf16x8 af[2], bfr[2];
      #pragma unroll
      for (int mt = 0; mt < 2; mt++) {
        int row = wm * 32 + mt * 16 + l15;
        af[mt] = *(const bf16x8*)&Sa[row * 32 + ((quad ^ ((row >> 1) & 3)) * 8)];
      }
      #pragma unroll
      for (int nt = 0; nt < 2; nt++) {
        int row = wn * 32 + nt * 16 + l15;
        bfr[nt] = *(const bf16x8*)&Sb[row * 32 + ((quad ^ ((row >> 1) & 3)) * 8)];
      }
      #pragma unroll
      for (int mt = 0; mt < 2; mt++)
        #pragma unroll
        for (int nt = 0; nt < 2; nt++)
          acc[mt][nt] = __builtin_amdgcn_mfma_f32_16x16x32_bf16(af[mt], bfr[nt], acc[mt][nt], 0, 0, 0);
    }
    __syncthreads();   // drains this step's prefetch (overlapped with the MFMAs above)
  }

  int n0 = in_ * 128;
  #pragma unroll
  for (int mt = 0; mt < 2; mt++) {
    #pragma unroll
    for (int nt = 0; nt < 2; nt++) {
      int colg = n0 + wn * 32 + nt * 16 + l15;
      #pragma unroll
      for (int r = 0; r < 4; r++) {
        int rowg = im * 128 + wm * 32 + mt * 16 + quad * 4 + r;
        C[(size_t)rowg * ldC + colg] = f2bf(acc[mt][nt][r]);
      }
    }
  }
}

// ---------------- qfused: g-GEMM + GELU + MFMA-angles + P0 + S-GEMM + |S|^2 + out-GEMM ----
// 256 blocks x 1024 thr (16 waves); block owns 64 samples. 1 block/CU, 4 waves/SIMD.
// Barrier-shadow loads: all 8 Wg frags preloaded above the As DMA barrier (fly under
// the HBM wait); first Uri frags hoisted above the P0s barrier; Gt frags above the Ts
// barrier. Same loads, same consumption order -> bit-identical numerics.
// LDS 100 KB: As 32K | gs|Ts 32K | P0s(prt) 32K | csw 4K
__global__ __launch_bounds__(1024, 4)
void qfused_kernel(const unsigned short* __restrict__ xagg,
                   const unsigned short* __restrict__ Wg,
                   const float* __restrict__ bg,
                   const float* __restrict__ Wpre, const float* __restrict__ bpre,
                   const unsigned short* __restrict__ Uri,
                   const _Float16* __restrict__ Gt,
                   const float* __restrict__ bpost,
                   float* __restrict__ out) {
  __shared__ __align__(16) char smemraw[102400];
  unsigned short* As  = (unsigned short*)smemraw;            // 32 KB swz panels [8][64][32] bf16
  unsigned short* gs  = (unsigned short*)(smemraw + 32768);  // 32 KB swz panels [8][64][32] bf16
  _Float16*       Ts  = (_Float16*)(smemraw + 32768);        //   (reused: f16 T panels, same swz)
  unsigned short* P0s = (unsigned short*)(smemraw + 65536);  // 32 KB swz panels
  float*          prt = (float*)(smemraw + 65536);           //   (early reuse: [8][64][8] f32 partials)
  float*          csw = (float*)(smemraw + 98304);           // 4 KB [64][16]: cw[8] | sw[8] per row

  int t = threadIdx.x;
  int wv = t >> 6, lane = t & 63;
  int l15 = lane & 15, quad = lane >> 4;

  const unsigned short* Ab = xagg + (size_t)blockIdx.x * 64 * 256;

  // ---- stage xagg A-tile (64x256) into LDS ONCE (issue), then preload ALL Wg
  //      fragments for this wave's columns so they fly under the DMA wait ----
  #pragma unroll
  for (int q = 0; q < 2; q++) {
    int sidx = q * 1024 + t;           // 0..2047 slots of 16B
    int kb = sidx >> 8;                // k-panel 0..7
    int r  = (sidx >> 2) & 63;         // row 0..63
    int c  = (sidx & 3) ^ ((r >> 1) & 3);
    async_ld16(Ab + (size_t)r * 256 + kb * 32 + c * 8, &As[sidx * 8]);
  }
  const unsigned short* Wp = Wg + (size_t)(wv * 16 + l15) * 256 + quad * 8;
  bf16x8 wf[8];
  #pragma unroll
  for (int k8 = 0; k8 < 8; k8++) wf[k8] = *(const bf16x8*)(Wp + k8 * 32);
  __syncthreads();   // As ready (Wg frags arrived during the same drain)

  // ---- stage A: g = GELU(xagg @ Wg^T + bg); wave wv owns cols wv*16..+15 ----
  f32x4 acc[4] = {};
  #pragma unroll
  for (int k8 = 0; k8 < 8; k8++) {
    #pragma unroll
    for (int mt = 0; mt < 4; mt++) {
      int row = mt * 16 + l15;
      bf16x8 af = *(const bf16x8*)&As[k8 * 2048 + row * 32 + ((quad ^ ((row >> 1) & 3)) * 8)];
      acc[mt] = __builtin_amdgcn_mfma_f32_16x16x32_bf16(af, wf[k8], acc[mt], 0, 0, 0);
    }
  }
  {
    int col = wv * 16 + l15;
    float bgl = bg[col];
    int kbc = col >> 5, chunk = (col >> 3) & 3, e = col & 7;
    #pragma unroll
    for (int mt = 0; mt < 4; mt++) {
      #pragma unroll
      for (int r = 0; r < 4; r++) {
        int row = mt * 16 + quad * 4 + r;
        float v = acc[mt][r] + bgl;
        v = 0.5f * v * (1.0f + fast_erf(v * 0.7071067811865475f));
        *(unsigned short*)((char*)gs + kbc * 4096 + row * 64 +
                           ((chunk ^ ((row >> 1) & 3)) << 4) + e * 2) = f2bf(v);
      }
    }
  }
  __syncthreads();   // gs complete

  // ---- angle GEMM: ang = g @ Wpre^T; wave pair (k8 = wv>>1) x M-half (mh = wv&1) ----
  {
    int k8 = wv >> 1, mh = wv & 1;
    const float* wrow = Wpre + (size_t)(l15 & 7) * 256 + k8 * 32 + quad * 8;
    float4 wa = *(const float4*)wrow;
    float4 wb = *(const float4*)(wrow + 4);
    float v8[8] = {wa.x, wa.y, wa.z, wa.w, wb.x, wb.y, wb.z, wb.w};
    bf16x8 whi, wlo;
    #pragma unroll
    for (int j = 0; j < 8; j++) {
      unsigned short h = f2bf(v8[j]);
      whi[j] = (short)h;
      wlo[j] = (short)f2bf(v8[j] - bf2f(h));
    }
    f32x4 aacc[2] = {};
    #pragma unroll
    for (int mt = 0; mt < 2; mt++) {
      int row = mh * 32 + mt * 16 + l15;
      bf16x8 ga = *(const bf16x8*)((char*)gs + k8 * 4096 + row * 64 +
                                   ((quad ^ ((row >> 1) & 3)) << 4));
      aacc[mt] = __builtin_amdgcn_mfma_f32_16x16x32_bf16(ga, whi, aacc[mt], 0, 0, 0);
      aacc[mt] = __builtin_amdgcn_mfma_f32_16x16x32_bf16(ga, wlo, aacc[mt], 0, 0, 0);
    }
    if (l15 < 8) {
      #pragma unroll
      for (int mt = 0; mt < 2; mt++)
        #pragma unroll
        for (int r = 0; r < 4; r++)
          prt[k8 * 512 + (mh * 32 + mt * 16 + quad * 4 + r) * 8 + l15] = aacc[mt][r];
    }
  }
  __syncthreads();   // partials complete

  // ---- one transcendental set per (row,w): 512 threads ----
  if (t < 512) {
    float s = 0.f;
    #pragma unroll
    for (int k = 0; k < 8; k++) s += prt[k * 512 + t];
    float th = (0.5f * PI_F) * fast_tanh(s + bpre[t & 7]);
    int row = t >> 3, w = t & 7;
    csw[row * 16 + w] = __cosf(th);
    csw[row * 16 + 8 + w] = __sinf(th);
  }
  __syncthreads();   // csw complete (partials consumed -> P0s region free)

  // ---- RY product state -> P0s panels; wave wv owns rows wv*4..+3 ----
  #pragma unroll
  for (int rr = 0; rr < 4; rr++) {
    int row = wv * 4 + rr;
    float4 c0 = *(const float4*)&csw[row * 16];
    float4 c1 = *(const float4*)&csw[row * 16 + 4];
    float4 s0 = *(const float4*)&csw[row * 16 + 8];
    float4 s1 = *(const float4*)&csw[row * 16 + 12];
    float cw[8] = {c0.x, c0.y, c0.z, c0.w, c1.x, c1.y, c1.z, c1.w};
    float sw[8] = {s0.x, s0.y, s0.z, s0.w, s1.x, s1.y, s1.z, s1.w};
    // amp index n = 4*lane + j : bits 0,1 = j ; bits 2..7 = lane bits 0..5
    float pl = 1.f;
    #pragma unroll
    for (int b = 0; b < 6; b++) pl *= ((lane >> b) & 1) ? sw[b + 2] : cw[b + 2];
    ushort4 o;
    o.x = f2bf(pl * cw[0] * cw[1]);
    o.y = f2bf(pl * sw[0] * cw[1]);
    o.z = f2bf(pl * cw[0] * sw[1]);
    o.w = f2bf(pl * sw[0] * sw[1]);
    int jj = lane & 7;
    int cswz = (jj >> 1) ^ ((row >> 1) & 3);
    *(ushort4*)((char*)P0s + (lane >> 3) * 4096 + row * 64 + cswz * 16 + (jj & 1) * 8) = o;
  }
  // hoist stage-B Uri fragment loads above the barrier (fly under the barrier wait)
  const unsigned short* Up = Uri + (size_t)(wv * 32 + l15) * 256 + quad * 8;
  bf16x8 ua[2][2];
  #pragma unroll
  for (int sl = 0; sl < 2; sl++)
    #pragma unroll
    for (int nt = 0; nt < 2; nt++)
      ua[sl][nt] = *(const bf16x8*)(Up + sl * 32 + nt * 4096);
  __syncthreads();   // P0s complete

  // ---- stage B: S = P0 @ Uri^T; wave wv owns T-col block wv (16 cols, re+im) ----
  // Uri interleaved: rows wv*32 + l15 (re), wv*32 + 16 + l15 (im).
  f32x4 acc1[4][2] = {};
  {
    #pragma unroll
    for (int k8 = 0; k8 < 8; k8++) {
      int cur = k8 & 1;
      #pragma unroll
      for (int mt = 0; mt < 4; mt++) {
        int row = mt * 16 + l15;
        bf16x8 pa = *(const bf16x8*)((char*)P0s + k8 * 4096 + row * 64 +
                                     ((quad ^ ((row >> 1) & 3)) << 4));
        acc1[mt][0] = __builtin_amdgcn_mfma_f32_16x16x32_bf16(pa, ua[cur][0], acc1[mt][0], 0, 0, 0);
        acc1[mt][1] = __builtin_amdgcn_mfma_f32_16x16x32_bf16(pa, ua[cur][1], acc1[mt][1], 0, 0, 0);
      }
      if (k8 < 6) {
        #pragma unroll
        for (int nt = 0; nt < 2; nt++)
          ua[cur][nt] = *(const bf16x8*)(Up + (k8 + 2) * 32 + nt * 4096);
      }
    }
  }

  // T = Sre^2 + Sim^2 -> Ts panels (reuses gs arena; same swizzle)
  {
    int colT = wv * 16 + l15;
    int kbc = colT >> 5, chunk = (colT >> 3) & 3, e = colT & 7;
    #pragma unroll
    for (int mt = 0; mt < 4; mt++) {
      #pragma unroll
      for (int r = 0; r < 4; r++) {
        int row = mt * 16 + quad * 4 + r;
        float tre = acc1[mt][0][r], tim = acc1[mt][1][r];
        *(_Float16*)((char*)Ts + kbc * 4096 + row * 64 +
                     ((chunk ^ ((row >> 1) & 3)) << 4) + e * 2)
            = (_Float16)(tre * tre + tim * tim);
      }
    }
  }
  // hoist stage-C Gt fragment loads above the barrier
  const _Float16* Gp = Gt + (size_t)(wv * 16 + l15) * 256 + quad * 8;
  f16x8 gf[2];
  gf[0] = *(const f16x8*)(Gp);
  gf[1] = *(const f16x8*)(Gp + 32);
  __syncthreads();   // Ts complete

  // ---- stage C: out = T @ Gt^T + bpost; wave wv owns out-cols wv*16..+15 ----
  f32x4 acc2[4] = {};
  {
    #pragma unroll
    for (int k8 = 0; k8 < 8; k8++) {
      int cur = k8 & 1;
      #pragma unroll
      for (int mt = 0; mt < 4; mt++) {
        int row = mt * 16 + l15;
        f16x8 tf = *(const f16x8*)((char*)Ts + k8 * 4096 + row * 64 +
                                   ((quad ^ ((row >> 1) & 3)) << 4));
        acc2[mt] = __builtin_amdgcn_mfma_f32_16x16x32_f16(tf, gf[cur], acc2[mt], 0, 0, 0);
      }
      if (k8 < 6) gf[cur] = *(const f16x8*)(Gp + (k8 + 2) * 32);
    }
  }

  // epilogue: bias + fp32 store with sample un-permute (s = i*16+b -> b*1024+i)
  {
    int col = wv * 16 + l15;
    float bp = bpost[col];
    #pragma unroll
    for (int mt = 0; mt < 4; mt++) {
      #pragma unroll
      for (int r = 0; r < 4; r++) {
        int row = mt * 16 + quad * 4 + r;
        int s = blockIdx.x * 64 + row;
        int orow = (s & 15) * 1024 + (s >> 4);
        out[(size_t)orow * 256 + col] = acc2[mt][r] + bp;
      }
    }
  }
}

// ---------------- host launch ----------------
extern "C" void kernel_launch(void* const* d_in, const int* in_sizes, int n_in,
                              void* d_out, int out_size, void* d_ws, size_t ws_size,
                              hipStream_t stream) {
  const float* x     = (const float*)d_in[0];  // (16,1024,256)
  const float* adj   = (const float*)d_in[1];  // (1024,1024)
  const float* Wg    = (const float*)d_in[2];  // (256,256)
  const float* bg    = (const float*)d_in[3];  // (256,)
  const float* Wpre  = (const float*)d_in[4];  // (8,256)
  const float* bpre  = (const float*)d_in[5];  // (8,)
  const float* qw    = (const float*)d_in[6];  // (2,8)
  const float* Wpost = (const float*)d_in[7];  // (256,8)
  const float* bpost = (const float*)d_in[8];  // (256,)
  float* out = (float*)d_out;                  // (16,1024,256)

  char* ws = (char*)d_ws;
  unsigned short* adj_bf  = (unsigned short*)(ws + 0);          // 2 MiB
  unsigned short* Wg_bf   = (unsigned short*)(ws + 2097152);    // 128 KiB
  unsigned short* xT_bf   = (unsigned short*)(ws + 2228224);    // 8 MiB  (4096 x 1024)
  unsigned short* xagg_bf = (unsigned short*)(ws + 10616832);   // 8 MiB  (16384 x 256 view)
  unsigned short* Uri     = (unsigned short*)(ws + 19005440);   // 256 KiB (512 x 256)
  _Float16*       Gt      = (_Float16*)(ws + 19267584);         // 128 KiB (256 x 256)

  // 1) prep: adj/Wg cvt + U-builder (interleaved) + G-builder + x transpose
  prep_kernel<<<5264, 256, 0, stream>>>(adj, adj_bf, Wg, Wg_bf, qw, Uri,
                                        Wpost, Gt, x, xT_bf);

  // 2) xagg = adj @ X'  (1024 x 4096 x 1024, tile 128x128, BK=128, 16 waves) -> bf16
  gemm1_kernel<<<256, 1024, 0, stream>>>(adj_bf, xT_bf, xagg_bf, 1024, 32, 4096);

  // 3) fused: g-GEMM + GELU + MFMA-angles + P0 (LDS) + S-GEMM + |S|^2 + out-GEMM
  qfused_kernel<<<256, 1024, 0, stream>>>(xagg_bf, Wg_bf, bg, Wpre, bpre, Uri, Gt, bpost, out);
}